// Round 6
// baseline (801.132 us; speedup 1.0000x reference)
//
#include <hip/hip_runtime.h>
#include <hip/hip_cooperative_groups.h>
#include <hip/hip_bf16.h>
#include <hip/hip_fp16.h>

namespace cg = cooperative_groups;

// Problem constants (fixed by the reference)
#define N_GENES_MAX 5000
#define N_ELEM_MAX  4000000
#define PARAMS_PER_GENE 445
#define BLOCK 256

// R15: the harness-proven R9 pipeline (best: 189.7us) fused into ONE
// cooperative kernel. Cross-round bookkeeping shows ~15-20us fixed tax per
// dispatch (R9: 3 dispatches, ~124us of kernel time, 190 total; R14: 5
// dispatches, 307 total). Fusing build -> evalA -> evalB with grid.sync()
// removes 2 dispatch taxes and keeps the proven structure:
//  - 8B knots {loc f32, (h f16<<16)|(cdf-loc) f16}; two 8B loads per probe
//    (R11/R14 showed scattered 16B gathers cost ~3x scattered 8B -> worse).
//  - Stage split: phase A touches only g_k0 (5.0MB ~ per-XCD L2), phase B
//    touches g_k1+g_k2 (3.75MB, L2-resident). Midstate 8B/elem coalesced.
__device__ uint2 g_k0[(size_t)N_GENES_MAX * 128];
__device__ uint2 g_k1[(size_t)N_GENES_MAX * 64];
__device__ uint2 g_k2[(size_t)N_GENES_MAX * 32];
__device__ uint2 g_mid[N_ELEM_MAX];

static __device__ __forceinline__ unsigned f2h(float f) {
    union { __half h; unsigned short u; } c;
    c.h = __float2half_rn(f);
    return (unsigned)c.u;
}
static __device__ __forceinline__ float h2f(unsigned u) {
    union { unsigned short u; __half h; } c;
    c.u = (unsigned short)u;
    return __half2float(c.h);
}

// ---- wave-level primitives (64 lanes) ----
static __device__ __forceinline__ float wscan_incl(float v) {
    const int lane = threadIdx.x & 63;
    #pragma unroll
    for (int off = 1; off < 64; off <<= 1) {
        float u = __shfl_up(v, off, 64);
        if (lane >= off) v += u;
    }
    return v;
}
static __device__ __forceinline__ float wmax64(float v) {
    #pragma unroll
    for (int off = 32; off > 0; off >>= 1) v = fmaxf(v, __shfl_xor(v, off, 64));
    return v;
}
static __device__ __forceinline__ float wsum64(float v) {
    #pragma unroll
    for (int off = 32; off > 0; off >>= 1) v += __shfl_xor(v, off, 64);
    return v;
}

// ---------------------------------------------------------------------------
// Phase 1: build per-(gene,stage) knots (R8-verified logic). Runs inside the
// 256-thread cooperative block: threads 128..255 idle but hit all barriers.
// Grid-stride over G*3 tasks.
// ---------------------------------------------------------------------------
static __device__ void build_phase(const float* __restrict__ params, int G) {
    __shared__ float s2[2];
    __shared__ float s_scan[128];
    __shared__ float s_h[129];
    __shared__ float s_loc[128];
    __shared__ float s_cdf[128];

    const int tid  = threadIdx.x;
    const int lane = tid & 63;
    const int wv   = tid >> 6;          // 0..3; only 0,1 are active halves

    const int ntask = G * 3;
    for (int task = blockIdx.x; task < ntask; task += gridDim.x) {
        const int g = task / 3;
        const int t = task - g * 3;
        const int ns[3]   = {128, 64, 32};
        const int poff[3] = {0, 255, 382};

        const int n = ns[t];
        const int m = n - 1;
        const float* ph = params + (size_t)g * PARAMS_PER_GENE + poff[t];
        const float* pw = ph + n;

        const float uw = (tid < m) ? pw[tid] : -1e30f;
        float vmax = wmax64(uw);
        if (lane == 0 && wv < 2) s2[wv] = vmax;
        __syncthreads();
        const float mx = fmaxf(s2[0], s2[1]);
        __syncthreads();

        const float e = (tid < m) ? __expf(uw - mx) : 0.0f;

        float sc = wscan_incl(e);
        if (lane == 63 && wv < 2) s2[wv] = sc;
        __syncthreads();
        if (wv == 1) sc += s2[0];
        if (tid < 128) s_scan[tid] = sc;
        __syncthreads();

        const float S = s_scan[m - 1];
        const float invS = 1.0f / S;
        if (tid == 0) s_loc[0] = 0.0f;
        if (tid < m) s_loc[tid + 1] = (tid == m - 1) ? 1.0f : s_scan[tid] * invS;
        const float w_i = e * invS;

        const float eh = (tid < n) ? __expf(ph[tid]) : 0.0f;
        if (tid < 128) s_h[tid] = eh;
        if (tid == 0) s_h[128] = 0.0f;
        __syncthreads();

        const float term = (tid < m) ? 0.5f * (s_h[tid] + s_h[tid + 1]) * w_i : 0.0f;
        float ts = wsum64(term);
        if (lane == 0 && wv < 2) s2[wv] = ts;
        __syncthreads();
        const float area = s2[0] + s2[1];
        __syncthreads();

        const float ia = 1.0f / area;
        const float hgt = eh * ia;

        float c = wscan_incl(term * ia);
        if (lane == 63 && wv < 2) s2[wv] = c;
        __syncthreads();
        if (wv == 1) c += s2[0];
        if (tid < 128) s_scan[tid] = c;
        __syncthreads();

        if (tid == 0) s_cdf[0] = 0.0f;
        if (tid < m) s_cdf[tid + 1] = (tid == m - 1) ? 1.0f : s_scan[tid];
        __syncthreads();

        if (tid < n) {
            const float loc = s_loc[tid];
            uint2 kt;
            kt.x = __float_as_uint(loc);
            kt.y = (f2h(hgt) << 16) | f2h(s_cdf[tid] - loc);
            if (t == 0)      g_k0[(size_t)g * 128 + tid] = kt;
            else if (t == 1) g_k1[(size_t)g * 64 + tid] = kt;
            else             g_k2[(size_t)g * 32 + tid] = kt;
        }
        __syncthreads();   // protect shared reuse across task iterations
    }
}

// ---------------------------------------------------------------------------
// Stage evaluation from packed 8B knots (R9-proven logic, two 8B loads).
// ---------------------------------------------------------------------------
template <int K>
static __device__ __forceinline__ void stage(const uint2* __restrict__ kn,
                                             float& x, float& lad) {
    int b = (int)(x * (float)(K - 1));
    b = (b < 0) ? 0 : ((b > K - 2) ? K - 2 : b);
    uint2 k0 = kn[b];
    uint2 k1 = kn[b + 1];
    float l0 = __uint_as_float(k0.x);
    float l1 = __uint_as_float(k1.x);
    while (b > 0 && l0 > x) {
        --b;
        k1 = k0; l1 = l0;
        k0 = kn[b]; l0 = __uint_as_float(k0.x);
    }
    while (b < K - 2 && l1 <= x) {
        ++b;
        k0 = k1; l0 = l1;
        k1 = kn[b + 1]; l1 = __uint_as_float(k1.x);
    }
    const float lh = h2f(k0.y >> 16);
    const float rh = h2f(k1.y >> 16);
    const float lc = l0 + h2f(k0.y & 0xffffu);
    const float w  = l1 - l0;
    const float alpha = (x - l0) / w;
    float o = (0.5f * (rh - lh) * w) * alpha * alpha + (lh * w) * alpha + lc;
    o = fminf(fmaxf(o, 0.0f), 1.0f);
    lad += __logf(alpha * (rh - lh) + lh);
    x = o;
}

typedef float fvec2 __attribute__((ext_vector_type(2)));
typedef int   ivec2 __attribute__((ext_vector_type(2)));
typedef unsigned uvec4 __attribute__((ext_vector_type(4)));

// ---------------------------------------------------------------------------
// Phase 2: stage0 only (table 5.0MB). Grid-stride over element pairs.
// ---------------------------------------------------------------------------
static __device__ void evalA_phase(const float* __restrict__ x_in,
                                   const int* __restrict__ gix, int N) {
    const int T = (int)(gridDim.x * blockDim.x);
    const int npairs = (N + 1) >> 1;
    for (int i = (int)(blockIdx.x * blockDim.x + threadIdx.x); i < npairs; i += T) {
        const int i2 = i * 2;
        if (i2 + 1 < N) {
            const fvec2 xv = __builtin_nontemporal_load((const fvec2*)(x_in + i2));
            const ivec2 gv = __builtin_nontemporal_load((const ivec2*)(gix + i2));
            float x0 = xv.x, x1 = xv.y;
            float l0 = 0.0f, l1 = 0.0f;
            stage<128>(g_k0 + (size_t)gv.x * 128, x0, l0);
            stage<128>(g_k0 + (size_t)gv.y * 128, x1, l1);
            uvec4 mid;
            mid.x = __float_as_uint(x0);
            mid.y = ((unsigned)gv.x << 16) | f2h(l0);
            mid.z = __float_as_uint(x1);
            mid.w = ((unsigned)gv.y << 16) | f2h(l1);
            __builtin_nontemporal_store(mid, (uvec4*)(g_mid + i2));
        } else {
            float x0 = x_in[i2];
            float l0 = 0.0f;
            const int g = gix[i2];
            stage<128>(g_k0 + (size_t)g * 128, x0, l0);
            uint2 m;
            m.x = __float_as_uint(x0);
            m.y = ((unsigned)g << 16) | f2h(l0);
            g_mid[i2] = m;
        }
    }
}

// ---------------------------------------------------------------------------
// Phase 3: stages 1+2 (tables 3.75MB, L2-resident). Grid-stride over pairs.
// ---------------------------------------------------------------------------
static __device__ void evalB_phase(float* __restrict__ out, int N) {
    const int T = (int)(gridDim.x * blockDim.x);
    const int npairs = (N + 1) >> 1;
    for (int i = (int)(blockIdx.x * blockDim.x + threadIdx.x); i < npairs; i += T) {
        const int i2 = i * 2;
        if (i2 + 1 < N) {
            const uvec4 mid = __builtin_nontemporal_load((const uvec4*)(g_mid + i2));
            float x0 = __uint_as_float(mid.x);
            float x1 = __uint_as_float(mid.z);
            const int g0 = (int)(mid.y >> 16);
            const int g1 = (int)(mid.w >> 16);
            float l0 = h2f(mid.y & 0xffffu);
            float l1 = h2f(mid.w & 0xffffu);
            stage<64>(g_k1 + (size_t)g0 * 64, x0, l0);
            stage<64>(g_k1 + (size_t)g1 * 64, x1, l1);
            stage<32>(g_k2 + (size_t)g0 * 32, x0, l0);
            stage<32>(g_k2 + (size_t)g1 * 32, x1, l1);
            fvec2 o0; o0.x = x0; o0.y = x1;
            fvec2 o1; o1.x = l0; o1.y = l1;
            __builtin_nontemporal_store(o0, (fvec2*)(out + i2));
            __builtin_nontemporal_store(o1, (fvec2*)(out + N + i2));
        } else {
            const uint2 mid = g_mid[i2];
            float x0 = __uint_as_float(mid.x);
            const int g0 = (int)(mid.y >> 16);
            float l0 = h2f(mid.y & 0xffffu);
            stage<64>(g_k1 + (size_t)g0 * 64, x0, l0);
            stage<32>(g_k2 + (size_t)g0 * 32, x0, l0);
            out[i2] = x0;
            out[N + i2] = l0;
        }
    }
}

// ---------------------------------------------------------------------------
// The single fused cooperative kernel.
// __launch_bounds__(256, 8): 8 waves/SIMD -> 32 waves/CU -> 8 blocks/CU of
// 256 threads co-resident, so a 2048-block cooperative grid fits.
// ---------------------------------------------------------------------------
__global__ void __launch_bounds__(BLOCK, 8)
fused_kernel(const float* __restrict__ x_in, const int* __restrict__ gix,
             const float* __restrict__ params, float* __restrict__ out,
             int N, int G) {
    cg::grid_group grid = cg::this_grid();

    build_phase(params, G);
    __threadfence();
    grid.sync();

    evalA_phase(x_in, gix, N);
    __threadfence();
    grid.sync();

    evalB_phase(out, N);
}

// ---------------------------------------------------------------------------
extern "C" void kernel_launch(void* const* d_in, const int* in_sizes, int n_in,
                              void* d_out, int out_size, void* d_ws, size_t ws_size,
                              hipStream_t stream) {
    const float* x      = (const float*)d_in[0];
    const int*   gix    = (const int*)d_in[1];
    const float* params = (const float*)d_in[2];
    float* out = (float*)d_out;

    int N = in_sizes[0];
    int G = in_sizes[2] / PARAMS_PER_GENE;

    // Size the cooperative grid to guaranteed co-residency.
    int maxb = 0;
    if (hipOccupancyMaxActiveBlocksPerMultiprocessor(
            &maxb, (const void*)fused_kernel, BLOCK, 0) != hipSuccess || maxb < 1)
        maxb = 7;   // conservative fallback
    if (maxb > 8) maxb = 8;
    int nblk = 256 * maxb;          // 256 CUs
    if (nblk > 2048) nblk = 2048;

    void* args[] = {(void*)&x, (void*)&gix, (void*)&params, (void*)&out,
                    (void*)&N, (void*)&G};
    hipLaunchCooperativeKernel((const void*)fused_kernel,
                               dim3(nblk), dim3(BLOCK), args, 0, stream);
}

// Round 7
// 189.776 us; speedup vs baseline: 4.2215x; 4.2215x over previous
//
#include <hip/hip_runtime.h>
#include <hip/hip_bf16.h>
#include <hip/hip_fp16.h>

// Problem constants (fixed by the reference)
#define N_GENES_MAX 5000
#define N_ELEM_MAX  4000000
#define PARAMS_PER_GENE 445

// R16 = R9 restored (harness-proven 189.7us). Session cost model (R10-R15):
//  - Eval is bound by L2 scattered lane-request throughput (~16/cy/XCD),
//    NOT latency (ILP-4 null, R10), NOT HBM (15%), NOT VALU (25%).
//  - Tables must be <=4MB per phase so they're resident in EVERY XCD's L2:
//    pass A touches only g_k0 (5.0MB), pass B g_k1+g_k2 (3.75MB).
//    16B records double request cost and break residency (R11/R14).
//  - Random small scatters cost a 64B line writeback each (R12) -> all
//    writes coalesced; midstate 8B/elem {x' f32, (gene<<16)|lad0 f16}.
//  - Fixed harness overhead ~65us is per-iteration, NOT per-dispatch;
//    cooperative fusion of the 3 kernels regressed 5x (R15). Keep 3 launches.
__device__ uint2 g_k0[(size_t)N_GENES_MAX * 128];
__device__ uint2 g_k1[(size_t)N_GENES_MAX * 64];
__device__ uint2 g_k2[(size_t)N_GENES_MAX * 32];
__device__ uint2 g_mid[N_ELEM_MAX];

static __device__ __forceinline__ unsigned f2h(float f) {
    union { __half h; unsigned short u; } c;
    c.h = __float2half_rn(f);
    return (unsigned)c.u;
}
static __device__ __forceinline__ float h2f(unsigned u) {
    union { unsigned short u; __half h; } c;
    c.u = (unsigned short)u;
    return __half2float(c.h);
}

// ---- wave-level primitives (64 lanes) ----
static __device__ __forceinline__ float wscan_incl(float v) {
    const int lane = threadIdx.x & 63;
    #pragma unroll
    for (int off = 1; off < 64; off <<= 1) {
        float u = __shfl_up(v, off, 64);
        if (lane >= off) v += u;
    }
    return v;
}
static __device__ __forceinline__ float wmax64(float v) {
    #pragma unroll
    for (int off = 32; off > 0; off >>= 1) v = fmaxf(v, __shfl_xor(v, off, 64));
    return v;
}
static __device__ __forceinline__ float wsum64(float v) {
    #pragma unroll
    for (int off = 32; off > 0; off >>= 1) v += __shfl_xor(v, off, 64);
    return v;
}

// ---------------------------------------------------------------------------
// Kernel 1: build per-(gene,stage) knots. grid=(G,3), block=128 (2 waves).
// (R8-verified: wave-shuffle scans + 2-element LDS cross-wave combine.)
// ---------------------------------------------------------------------------
__global__ void build_knots(const float* __restrict__ params) {
    const int g = blockIdx.x;
    const int t = blockIdx.y;
    const int ns[3]   = {128, 64, 32};
    const int poff[3] = {0, 255, 382};

    const int n = ns[t];
    const int m = n - 1;
    const float* ph = params + (size_t)g * PARAMS_PER_GENE + poff[t];
    const float* pw = ph + n;

    __shared__ float s2[2];
    __shared__ float s_scan[128];
    __shared__ float s_h[129];
    __shared__ float s_loc[128];
    __shared__ float s_cdf[128];

    const int tid  = threadIdx.x;
    const int lane = tid & 63;
    const int wv   = tid >> 6;

    const float uw = (tid < m) ? pw[tid] : -1e30f;
    float vmax = wmax64(uw);
    if (lane == 0) s2[wv] = vmax;
    __syncthreads();
    const float mx = fmaxf(s2[0], s2[1]);
    __syncthreads();

    const float e = (tid < m) ? __expf(uw - mx) : 0.0f;

    float sc = wscan_incl(e);
    if (lane == 63) s2[wv] = sc;
    __syncthreads();
    if (wv == 1) sc += s2[0];
    s_scan[tid] = sc;
    __syncthreads();

    const float S = s_scan[m - 1];
    const float invS = 1.0f / S;
    if (tid == 0) s_loc[0] = 0.0f;
    if (tid < m) s_loc[tid + 1] = (tid == m - 1) ? 1.0f : s_scan[tid] * invS;
    const float w_i = e * invS;

    const float eh = (tid < n) ? __expf(ph[tid]) : 0.0f;
    s_h[tid] = eh;
    if (tid == 0) s_h[128] = 0.0f;
    __syncthreads();

    const float term = (tid < m) ? 0.5f * (s_h[tid] + s_h[tid + 1]) * w_i : 0.0f;
    float ts = wsum64(term);
    if (lane == 0) s2[wv] = ts;
    __syncthreads();
    const float area = s2[0] + s2[1];
    __syncthreads();

    const float ia = 1.0f / area;
    const float hgt = eh * ia;

    float c = wscan_incl(term * ia);
    if (lane == 63) s2[wv] = c;
    __syncthreads();
    if (wv == 1) c += s2[0];
    s_scan[tid] = c;
    __syncthreads();

    if (tid == 0) s_cdf[0] = 0.0f;
    if (tid < m) s_cdf[tid + 1] = (tid == m - 1) ? 1.0f : s_scan[tid];
    __syncthreads();

    if (tid < n) {
        const float loc = s_loc[tid];
        uint2 kt;
        kt.x = __float_as_uint(loc);
        kt.y = (f2h(hgt) << 16) | f2h(s_cdf[tid] - loc);
        if (t == 0)      g_k0[(size_t)g * 128 + tid] = kt;
        else if (t == 1) g_k1[(size_t)g * 64 + tid] = kt;
        else             g_k2[(size_t)g * 32 + tid] = kt;
    }
}

// ---------------------------------------------------------------------------
// Stage evaluation from packed knots (verified R8 logic).
// ---------------------------------------------------------------------------
template <int K>
static __device__ __forceinline__ void stage(const uint2* __restrict__ kn,
                                             float& x, float& lad) {
    int b = (int)(x * (float)(K - 1));
    b = (b < 0) ? 0 : ((b > K - 2) ? K - 2 : b);
    uint2 k0 = kn[b];
    uint2 k1 = kn[b + 1];
    float l0 = __uint_as_float(k0.x);
    float l1 = __uint_as_float(k1.x);
    while (b > 0 && l0 > x) {
        --b;
        k1 = k0; l1 = l0;
        k0 = kn[b]; l0 = __uint_as_float(k0.x);
    }
    while (b < K - 2 && l1 <= x) {
        ++b;
        k0 = k1; l0 = l1;
        k1 = kn[b + 1]; l1 = __uint_as_float(k1.x);
    }
    const float lh = h2f(k0.y >> 16);
    const float rh = h2f(k1.y >> 16);
    const float lc = l0 + h2f(k0.y & 0xffffu);
    const float w  = l1 - l0;
    const float alpha = (x - l0) / w;
    float o = (0.5f * (rh - lh) * w) * alpha * alpha + (lh * w) * alpha + lc;
    o = fminf(fmaxf(o, 0.0f), 1.0f);
    lad += __logf(alpha * (rh - lh) + lh);
    x = o;
}

typedef float fvec2 __attribute__((ext_vector_type(2)));
typedef int   ivec2 __attribute__((ext_vector_type(2)));
typedef unsigned uvec4 __attribute__((ext_vector_type(4)));

// ---------------------------------------------------------------------------
// Kernel 2a: pass A — stage0 only (table 5.0 MB). Writes midstate.
// ---------------------------------------------------------------------------
__global__ void spline_evalA(const float* __restrict__ x_in,
                             const int* __restrict__ gix, int N) {
    const int i = blockIdx.x * blockDim.x + threadIdx.x;
    const int i2 = i * 2;
    if (i2 + 1 < N) {
        const fvec2 xv = __builtin_nontemporal_load((const fvec2*)(x_in + i2));
        const ivec2 gv = __builtin_nontemporal_load((const ivec2*)(gix + i2));
        float x0 = xv.x, x1 = xv.y;
        float l0 = 0.0f, l1 = 0.0f;
        stage<128>(g_k0 + (size_t)gv.x * 128, x0, l0);
        stage<128>(g_k0 + (size_t)gv.y * 128, x1, l1);
        uvec4 mid;
        mid.x = __float_as_uint(x0);
        mid.y = ((unsigned)gv.x << 16) | f2h(l0);
        mid.z = __float_as_uint(x1);
        mid.w = ((unsigned)gv.y << 16) | f2h(l1);
        __builtin_nontemporal_store(mid, (uvec4*)(g_mid + i2));
    } else if (i2 < N) {
        float x0 = x_in[i2];
        float l0 = 0.0f;
        const int g = gix[i2];
        stage<128>(g_k0 + (size_t)g * 128, x0, l0);
        uint2 m;
        m.x = __float_as_uint(x0);
        m.y = ((unsigned)g << 16) | f2h(l0);
        g_mid[i2] = m;
    }
}

// ---------------------------------------------------------------------------
// Kernel 2b: pass B — stages 1+2 (tables 3.75 MB, L2-resident). Writes out.
// ---------------------------------------------------------------------------
__global__ void spline_evalB(float* __restrict__ out, int N) {
    const int i = blockIdx.x * blockDim.x + threadIdx.x;
    const int i2 = i * 2;
    if (i2 + 1 < N) {
        const uvec4 mid = __builtin_nontemporal_load((const uvec4*)(g_mid + i2));
        float x0 = __uint_as_float(mid.x);
        float x1 = __uint_as_float(mid.z);
        const int g0 = (int)(mid.y >> 16);
        const int g1 = (int)(mid.w >> 16);
        float l0 = h2f(mid.y & 0xffffu);
        float l1 = h2f(mid.w & 0xffffu);
        stage<64>(g_k1 + (size_t)g0 * 64, x0, l0);
        stage<64>(g_k1 + (size_t)g1 * 64, x1, l1);
        stage<32>(g_k2 + (size_t)g0 * 32, x0, l0);
        stage<32>(g_k2 + (size_t)g1 * 32, x1, l1);
        fvec2 o0; o0.x = x0; o0.y = x1;
        fvec2 o1; o1.x = l0; o1.y = l1;
        __builtin_nontemporal_store(o0, (fvec2*)(out + i2));
        __builtin_nontemporal_store(o1, (fvec2*)(out + N + i2));
    } else if (i2 < N) {
        const uint2 mid = g_mid[i2];
        float x0 = __uint_as_float(mid.x);
        const int g0 = (int)(mid.y >> 16);
        float l0 = h2f(mid.y & 0xffffu);
        stage<64>(g_k1 + (size_t)g0 * 64, x0, l0);
        stage<32>(g_k2 + (size_t)g0 * 32, x0, l0);
        out[i2] = x0;
        out[N + i2] = l0;
    }
}

// ---------------------------------------------------------------------------
extern "C" void kernel_launch(void* const* d_in, const int* in_sizes, int n_in,
                              void* d_out, int out_size, void* d_ws, size_t ws_size,
                              hipStream_t stream) {
    const float* x      = (const float*)d_in[0];
    const int*   gix    = (const int*)d_in[1];
    const float* params = (const float*)d_in[2];
    float* out = (float*)d_out;

    const int N = in_sizes[0];
    const int G = in_sizes[2] / PARAMS_PER_GENE;

    build_knots<<<dim3(G, 3), 128, 0, stream>>>(params);

    const int block = 256;
    const int nh = (N + 1) / 2;
    const int grid = (nh + block - 1) / block;
    spline_evalA<<<grid, block, 0, stream>>>(x, gix, N);
    spline_evalB<<<grid, block, 0, stream>>>(out, N);
}